// Round 1
// baseline (2143.782 us; speedup 1.0000x reference)
//
#include <hip/hip_runtime.h>
#include <hip/hip_bf16.h>

#define N_NODES 100000
#define N_EDGES 1600000
#define DIM 128
#define N_GRAPH 512
#define N_OUT 16
#define N_LAYERS 4
#define BN_EPS 1e-5f

// ---------------- CSR build ----------------
__global__ void hist_kernel(const int* __restrict__ dst, int* __restrict__ deg, int E) {
    int e = blockIdx.x * 256 + threadIdx.x;
    if (e < E) atomicAdd(&deg[dst[e]], 1);
}

__global__ __launch_bounds__(1024) void scan1_kernel(const int* __restrict__ deg,
                                                     int* __restrict__ ptr,
                                                     int* __restrict__ bsum, int N) {
    __shared__ int tmp[1024];
    int t = threadIdx.x;
    int i = blockIdx.x * 1024 + t;
    int v = (i < N) ? deg[i] : 0;
    tmp[t] = v;
    __syncthreads();
    int acc = v;
    for (int off = 1; off < 1024; off <<= 1) {
        int add = (t >= off) ? tmp[t - off] : 0;
        __syncthreads();
        acc += add;
        tmp[t] = acc;
        __syncthreads();
    }
    if (i < N) ptr[i] = acc - v;          // exclusive scan, block-local
    if (t == 1023) bsum[blockIdx.x] = acc; // block total
}

__global__ void scan2_kernel(int* __restrict__ bsum, int* __restrict__ ptr, int nb, int N) {
    __shared__ int tmp[128];
    int t = threadIdx.x;
    int v = (t < nb) ? bsum[t] : 0;
    tmp[t] = v;
    __syncthreads();
    int acc = v;
    for (int off = 1; off < 128; off <<= 1) {
        int add = (t >= off) ? tmp[t - off] : 0;
        __syncthreads();
        acc += add;
        tmp[t] = acc;
        __syncthreads();
    }
    if (t < nb) bsum[t] = acc - v;  // exclusive over block totals
    if (t == 127) ptr[N] = acc;     // total == E
}

__global__ void scan3_kernel(int* __restrict__ ptr, int* __restrict__ cursor,
                             const int* __restrict__ bsum, int N) {
    int i = blockIdx.x * 256 + threadIdx.x;
    if (i < N) {
        int v = ptr[i] + bsum[i >> 10];
        ptr[i] = v;
        cursor[i] = v;
    }
}

__global__ void fill_kernel(const int* __restrict__ src, const int* __restrict__ dst,
                            int* __restrict__ cursor, int* __restrict__ csr, int E) {
    int e = blockIdx.x * 256 + threadIdx.x;
    if (e < E) {
        int slot = atomicAdd(&cursor[dst[e]], 1);
        csr[slot] = src[e];
    }
}

__global__ void gptr_kernel(const int* __restrict__ gid, int* __restrict__ gptr, int N, int G) {
    int g = blockIdx.x * 256 + threadIdx.x;
    if (g > G) return;
    int lo = 0, hi = N;
    while (lo < hi) {
        int mid = (lo + hi) >> 1;
        if (gid[mid] < g) lo = mid + 1; else hi = mid;
    }
    gptr[g] = lo;
}

// ---------------- SpMM: out[n] = h[n] + sum_{j in in(n)} h[csr[j]] ----------------
__global__ void spmm_kernel(const float* __restrict__ h, const int* __restrict__ ptr,
                            const int* __restrict__ csr, float* __restrict__ out, int N) {
    int wave = (blockIdx.x * 256 + threadIdx.x) >> 6;  // one wave per node
    int lane = threadIdx.x & 63;
    if (wave >= N) return;
    const float2* hp = (const float2*)h;
    float2 acc = hp[(size_t)wave * 64 + lane];  // self term (eps = 0)
    int s0 = ptr[wave], s1 = ptr[wave + 1];
    for (int j = s0; j < s1; j++) {
        int s = csr[j];
        float2 v = hp[(size_t)s * 64 + lane];
        acc.x += v.x;
        acc.y += v.y;
    }
    ((float2*)out)[(size_t)wave * 64 + lane] = acc;
}

// ---------------- GEMM: Z = f(X) @ W  (M x 128) @ (128 x 128), + column stats ---------
// MODE 0: f(x) = x        MODE 1: f(x) = relu(x*a + b)  (a,b per input column)
template <int MODE>
__global__ __launch_bounds__(256) void gemm_kernel(
    const float* __restrict__ X, const float* __restrict__ W,
    const float* __restrict__ av, const float* __restrict__ bv,
    float* __restrict__ Z, float* __restrict__ gsum, float* __restrict__ gssq, int M) {
    __shared__ float xs[32 * 132];  // [k][row], padded
    __shared__ float ws[32 * 128];  // [k][col]
    __shared__ float lstat[256];

    int tid = threadIdx.x;
    int rowBase = blockIdx.x * 128;
    float acc[8][8];
#pragma unroll
    for (int r = 0; r < 8; r++)
#pragma unroll
        for (int c = 0; c < 8; c++) acc[r][c] = 0.f;

    int tc = tid & 15, tr = tid >> 4;
    int col0 = tc * 8, row0 = tr * 8;
    int xk = (tid & 7) * 4;  // k float4 offset for X staging
    int xr = tid >> 3;       // row base 0..31
    int wc = (tid & 31) * 4; // col float4 offset for W staging
    int wk = tid >> 5;       // k base 0..7

    for (int k0 = 0; k0 < 128; k0 += 32) {
        // stage X (transposed into xs[k][row])
#pragma unroll
        for (int i = 0; i < 4; i++) {
            int row = xr + i * 32;
            int rg = rowBase + row;
            float4 v = make_float4(0.f, 0.f, 0.f, 0.f);
            if (rg < M) {
                v = *(const float4*)(X + (size_t)rg * 128 + k0 + xk);
                if (MODE == 1) {
                    float4 a4 = *(const float4*)(av + k0 + xk);
                    float4 b4 = *(const float4*)(bv + k0 + xk);
                    v.x = fmaxf(v.x * a4.x + b4.x, 0.f);
                    v.y = fmaxf(v.y * a4.y + b4.y, 0.f);
                    v.z = fmaxf(v.z * a4.z + b4.z, 0.f);
                    v.w = fmaxf(v.w * a4.w + b4.w, 0.f);
                }
            }
            xs[(xk + 0) * 132 + row] = v.x;
            xs[(xk + 1) * 132 + row] = v.y;
            xs[(xk + 2) * 132 + row] = v.z;
            xs[(xk + 3) * 132 + row] = v.w;
        }
        // stage W
#pragma unroll
        for (int i = 0; i < 4; i++) {
            int k = wk + i * 8;
            *(float4*)&ws[k * 128 + wc] = *(const float4*)(W + (size_t)(k0 + k) * 128 + wc);
        }
        __syncthreads();
#pragma unroll
        for (int k = 0; k < 32; k++) {
            float4 xa = *(float4*)&xs[k * 132 + row0];
            float4 xb = *(float4*)&xs[k * 132 + row0 + 4];
            float4 wa = *(float4*)&ws[k * 128 + col0];
            float4 wb = *(float4*)&ws[k * 128 + col0 + 4];
            float x8[8] = {xa.x, xa.y, xa.z, xa.w, xb.x, xb.y, xb.z, xb.w};
            float w8[8] = {wa.x, wa.y, wa.z, wa.w, wb.x, wb.y, wb.z, wb.w};
#pragma unroll
            for (int r = 0; r < 8; r++)
#pragma unroll
                for (int c = 0; c < 8; c++) acc[r][c] += x8[r] * w8[c];
        }
        __syncthreads();
    }
    // store Z
#pragma unroll
    for (int r = 0; r < 8; r++) {
        int rg = rowBase + row0 + r;
        if (rg < M) {
            *(float4*)(Z + (size_t)rg * 128 + col0) =
                make_float4(acc[r][0], acc[r][1], acc[r][2], acc[r][3]);
            *(float4*)(Z + (size_t)rg * 128 + col0 + 4) =
                make_float4(acc[r][4], acc[r][5], acc[r][6], acc[r][7]);
        }
    }
    // column stats (sum, sumsq) -> LDS reduce -> global atomics
    lstat[tid] = 0.f;
    __syncthreads();
#pragma unroll
    for (int c = 0; c < 8; c++) {
        float s = 0.f, ss = 0.f;
#pragma unroll
        for (int r = 0; r < 8; r++) {
            float v = acc[r][c];
            s += v;
            ss += v * v;
        }
        atomicAdd(&lstat[col0 + c], s);
        atomicAdd(&lstat[128 + col0 + c], ss);
    }
    __syncthreads();
    if (tid < 128) {
        atomicAdd(&gsum[tid], lstat[tid]);
        atomicAdd(&gssq[tid], lstat[128 + tid]);
    }
}

// ---------------- BN finalize: a = gamma*rsqrt(v+eps), b = beta - m*a ----------------
__global__ void fin_kernel(const float* __restrict__ sum, const float* __restrict__ ssq,
                           const float* __restrict__ gamma, const float* __restrict__ beta,
                           float* __restrict__ a, float* __restrict__ b, float invN) {
    int c = threadIdx.x;
    float m = sum[c] * invN;
    float v = fmaxf(ssq[c] * invN - m * m, 0.f);
    float inv = rsqrtf(v + BN_EPS);
    float ac = gamma[c] * inv;
    a[c] = ac;
    b[c] = beta[c] - m * ac;
}

// ---------------- elementwise: out = relu(in*a + b) ----------------
__global__ void elem_kernel(const float* __restrict__ in, const float* __restrict__ a,
                            const float* __restrict__ b, float* __restrict__ out, int total4) {
    int i = blockIdx.x * 256 + threadIdx.x;
    if (i >= total4) return;
    float4 v = ((const float4*)in)[i];
    int c = (i * 4) & 127;
    v.x = fmaxf(v.x * a[c] + b[c], 0.f);
    v.y = fmaxf(v.y * a[c + 1] + b[c + 1], 0.f);
    v.z = fmaxf(v.z * a[c + 2] + b[c + 2], 0.f);
    v.w = fmaxf(v.w * a[c + 3] + b[c + 3], 0.f);
    ((float4*)out)[i] = v;
}

// ---------------- pooling: pooled[g][d] = sum over graph rows ----------------
__global__ void pool_kernel(const float* __restrict__ h, const int* __restrict__ gptr,
                            float* __restrict__ pooled) {
    int g = blockIdx.x;
    int d = threadIdx.x;  // 128
    int r0 = gptr[g], r1 = gptr[g + 1];
    float acc = 0.f;
    for (int r = r0; r < r1; r++) acc += h[(size_t)r * 128 + d];
    pooled[(size_t)g * 128 + d] = acc;
}

// ---------------- score + log_softmax ----------------
__global__ void score_kernel(const float* __restrict__ pooled, const float* __restrict__ Wp,
                             const float* __restrict__ bp, float* __restrict__ out, int G) {
    int g = blockIdx.x;
    int o = threadIdx.x;  // 64 threads, lanes 0..15 active
    float acc;
    if (o < 16) {
        acc = 0.f;
        for (int i = 0; i < N_LAYERS + 1; i++) {
            const float* pr = pooled + (size_t)i * G * 128 + (size_t)g * 128;
            const float* wp = Wp + (size_t)i * 128 * 16;
            float s = 0.f;
            for (int d = 0; d < 128; d++) s += pr[d] * wp[d * 16 + o];
            acc = acc + s + bp[i * 16 + o];
        }
    } else {
        acc = -1e30f;
    }
    float m = acc;
    for (int off = 8; off >= 1; off >>= 1) m = fmaxf(m, __shfl_xor(m, off, 16));
    float e = (o < 16) ? expf(acc - m) : 0.f;
    float se = e;
    for (int off = 8; off >= 1; off >>= 1) se += __shfl_xor(se, off, 16);
    if (o < 16) {
        out[g * 16 + o] = acc - m - logf(se);
        out[(size_t)G * 16 + g * 16 + o] = acc;
    }
}

extern "C" void kernel_launch(void* const* d_in, const int* in_sizes, int n_in,
                              void* d_out, int out_size, void* d_ws, size_t ws_size,
                              hipStream_t stream) {
    (void)in_sizes; (void)n_in; (void)out_size; (void)ws_size;
    const float* feat  = (const float*)d_in[0];
    const float* W1    = (const float*)d_in[1];
    const float* W2    = (const float*)d_in[2];
    const float* g_mlp = (const float*)d_in[3];
    const float* b_mlp = (const float*)d_in[4];
    const float* g_out = (const float*)d_in[5];
    const float* b_out = (const float*)d_in[6];
    const float* Wp    = (const float*)d_in[7];
    const float* bp    = (const float*)d_in[8];
    const int*   src   = (const int*)d_in[9];
    const int*   dst   = (const int*)d_in[10];
    const int*   gid   = (const int*)d_in[11];
    float* out = (float*)d_out;

    const int N = N_NODES, E = N_EDGES, D = DIM, G = N_GRAPH;
    char* w = (char*)d_ws;
    size_t off = 0;
    auto alloc = [&](size_t bytes) -> char* {
        char* p = w + off;
        off = (off + bytes + 255) & ~(size_t)255;
        return p;
    };
    float* bufA   = (float*)alloc((size_t)N * D * 4);
    float* bufB   = (float*)alloc((size_t)N * D * 4);
    int*   csr    = (int*)alloc((size_t)E * 4);
    int*   ptr    = (int*)alloc((size_t)(N + 1) * 4);
    int*   cursor = (int*)alloc((size_t)N * 4);
    int*   deg    = (int*)alloc((size_t)N * 4);
    int*   bsum   = (int*)alloc(128 * 4);
    int*   gptr   = (int*)alloc((G + 1) * 4);
    float* pooled = (float*)alloc((size_t)(N_LAYERS + 1) * G * D * 4);
    float* stats  = (float*)alloc(4 * 128 * 4);  // sum1 ssq1 sum2 ssq2
    float* ab     = (float*)alloc(4 * 128 * 4);  // a1 b1 a2 b2

    const int nScanBlocks = (N + 1023) / 1024;  // 98

    // ---- CSR build ----
    hipMemsetAsync(deg, 0, (size_t)N * 4, stream);
    hist_kernel<<<(E + 255) / 256, 256, 0, stream>>>(dst, deg, E);
    scan1_kernel<<<nScanBlocks, 1024, 0, stream>>>(deg, ptr, bsum, N);
    scan2_kernel<<<1, 128, 0, stream>>>(bsum, ptr, nScanBlocks, N);
    scan3_kernel<<<(N + 255) / 256, 256, 0, stream>>>(ptr, cursor, bsum, N);
    fill_kernel<<<(E + 255) / 256, 256, 0, stream>>>(src, dst, cursor, csr, E);
    gptr_kernel<<<3, 256, 0, stream>>>(gid, gptr, N, G);

    // ---- layer pipeline ----
    pool_kernel<<<G, 128, 0, stream>>>(feat, gptr, pooled);
    const float* h = feat;
    const int gemmGrid = (N + 127) / 128;
    for (int i = 0; i < N_LAYERS; i++) {
        hipMemsetAsync(stats, 0, 4 * 128 * 4, stream);
        spmm_kernel<<<N / 4, 256, 0, stream>>>(h, ptr, csr, bufB, N);
        gemm_kernel<0><<<gemmGrid, 256, 0, stream>>>(bufB, W1 + (size_t)i * D * D,
                                                     nullptr, nullptr, bufA,
                                                     stats, stats + 128, N);
        fin_kernel<<<1, 128, 0, stream>>>(stats, stats + 128, g_mlp + (size_t)i * D,
                                          b_mlp + (size_t)i * D, ab, ab + 128, 1.f / N);
        gemm_kernel<1><<<gemmGrid, 256, 0, stream>>>(bufA, W2 + (size_t)i * D * D,
                                                     ab, ab + 128, bufB,
                                                     stats + 256, stats + 384, N);
        fin_kernel<<<1, 128, 0, stream>>>(stats + 256, stats + 384, g_out + (size_t)i * D,
                                          b_out + (size_t)i * D, ab + 256, ab + 384, 1.f / N);
        elem_kernel<<<(N * D / 4 + 255) / 256, 256, 0, stream>>>(bufB, ab + 256, ab + 384,
                                                                 bufA, N * D / 4);
        pool_kernel<<<G, 128, 0, stream>>>(bufA, gptr, pooled + (size_t)(i + 1) * G * D);
        h = bufA;
    }
    score_kernel<<<G, 64, 0, stream>>>(pooled, Wp, bp, out, G);
}

// Round 2
// 945.044 us; speedup vs baseline: 2.2684x; 2.2684x over previous
//
#include <hip/hip_runtime.h>

#define N_NODES 100000
#define N_EDGES 1600000
#define DIM 128
#define N_GRAPH 512
#define N_LAYERS 4
#define BN_EPS 1e-5f
#define GEMM_BLOCKS ((N_NODES + 127) / 128)  // 782

typedef __attribute__((ext_vector_type(8))) short short8;
typedef __attribute__((ext_vector_type(4))) float f32x4;

__device__ __forceinline__ float b2f(unsigned short u) {
    union { unsigned int i; float f; } x;
    x.i = ((unsigned int)u) << 16;
    return x.f;
}
__device__ __forceinline__ unsigned short f2b(float f) {
    union { float f; unsigned int i; } x;
    x.f = f;
    unsigned int r = x.i + 0x7FFFu + ((x.i >> 16) & 1u);  // RNE
    return (unsigned short)(r >> 16);
}

// ---------------- CSR build ----------------
__global__ void hist_kernel(const int* __restrict__ dst, int* __restrict__ deg, int E) {
    int e = blockIdx.x * 256 + threadIdx.x;
    if (e < E) atomicAdd(&deg[dst[e]], 1);
}

__global__ __launch_bounds__(1024) void scan1_kernel(const int* __restrict__ deg,
                                                     int* __restrict__ ptr,
                                                     int* __restrict__ bsum, int N) {
    __shared__ int tmp[1024];
    int t = threadIdx.x;
    int i = blockIdx.x * 1024 + t;
    int v = (i < N) ? deg[i] : 0;
    tmp[t] = v;
    __syncthreads();
    int acc = v;
    for (int off = 1; off < 1024; off <<= 1) {
        int add = (t >= off) ? tmp[t - off] : 0;
        __syncthreads();
        acc += add;
        tmp[t] = acc;
        __syncthreads();
    }
    if (i < N) ptr[i] = acc - v;
    if (t == 1023) bsum[blockIdx.x] = acc;
}

__global__ void scan2_kernel(int* __restrict__ bsum, int* __restrict__ ptr, int nb, int N) {
    __shared__ int tmp[128];
    int t = threadIdx.x;
    int v = (t < nb) ? bsum[t] : 0;
    tmp[t] = v;
    __syncthreads();
    int acc = v;
    for (int off = 1; off < 128; off <<= 1) {
        int add = (t >= off) ? tmp[t - off] : 0;
        __syncthreads();
        acc += add;
        tmp[t] = acc;
        __syncthreads();
    }
    if (t < nb) bsum[t] = acc - v;
    if (t == 127) ptr[N] = acc;
}

__global__ void scan3_kernel(int* __restrict__ ptr, int* __restrict__ cursor,
                             const int* __restrict__ bsum, int N) {
    int i = blockIdx.x * 256 + threadIdx.x;
    if (i < N) {
        int v = ptr[i] + bsum[i >> 10];
        ptr[i] = v;
        cursor[i] = v;
    }
}

__global__ void fill_kernel(const int* __restrict__ src, const int* __restrict__ dst,
                            int* __restrict__ cursor, int* __restrict__ csr, int E) {
    int e = blockIdx.x * 256 + threadIdx.x;
    if (e < E) {
        int slot = atomicAdd(&cursor[dst[e]], 1);
        csr[slot] = src[e];
    }
}

__global__ void gptr_kernel(const int* __restrict__ gid, int* __restrict__ gptr, int N, int G) {
    int g = blockIdx.x * 256 + threadIdx.x;
    if (g > G) return;
    int lo = 0, hi = N;
    while (lo < hi) {
        int mid = (lo + hi) >> 1;
        if (gid[mid] < g) lo = mid + 1; else hi = mid;
    }
    gptr[g] = lo;
}

// ---------------- conversions ----------------
__global__ void cvt_feat_kernel(const float* __restrict__ f, ushort* __restrict__ o) {
    int i = blockIdx.x * 256 + threadIdx.x;  // per 4 elements
    if (i >= N_NODES * DIM / 4) return;
    float4 v = ((const float4*)f)[i];
    ushort4 u;
    u.x = f2b(v.x); u.y = f2b(v.y); u.z = f2b(v.z); u.w = f2b(v.w);
    ((ushort4*)o)[i] = u;
}

// Wt[mat][n][k] = W[mat][k][n]  (bf16, transposed for MFMA B-operand)
__global__ void cvtw_kernel(const float* __restrict__ W1, const float* __restrict__ W2,
                            ushort* __restrict__ Wt) {
    int blk = blockIdx.x;  // mat*128 + k
    int mat = blk >> 7, k = blk & 127;
    int n = threadIdx.x;
    const float* W = (mat < 4) ? (W1 + (size_t)mat * 16384) : (W2 + (size_t)(mat - 4) * 16384);
    Wt[(size_t)mat * 16384 + n * 128 + k] = f2b(W[k * 128 + n]);
}

// ---------------- SpMM (bf16): out[n] = h[n] + sum_{j in in(n)} h[csr[j]] ------------
__global__ __launch_bounds__(256) void spmm_bf16_kernel(const ushort* __restrict__ h,
                                                        const int* __restrict__ ptr,
                                                        const int* __restrict__ csr,
                                                        ushort* __restrict__ out) {
    int t = blockIdx.x * 256 + threadIdx.x;
    int node = t >> 5;  // 32 lanes per node (row = 256 B)
    int l = t & 31;
    if (node >= N_NODES) return;
    const ushort4* hp = (const ushort4*)h;
    size_t self = (size_t)node * 32 + l;
    ushort4 u = hp[self];
    float ax = b2f(u.x), ay = b2f(u.y), az = b2f(u.z), aw = b2f(u.w);
    int j = ptr[node], s1 = ptr[node + 1];
    for (; j + 1 < s1; j += 2) {
        int sa = csr[j], sb = csr[j + 1];
        ushort4 va = hp[(size_t)sa * 32 + l];
        ushort4 vb = hp[(size_t)sb * 32 + l];
        ax += b2f(va.x) + b2f(vb.x);
        ay += b2f(va.y) + b2f(vb.y);
        az += b2f(va.z) + b2f(vb.z);
        aw += b2f(va.w) + b2f(vb.w);
    }
    if (j < s1) {
        ushort4 va = hp[(size_t)csr[j] * 32 + l];
        ax += b2f(va.x); ay += b2f(va.y); az += b2f(va.z); aw += b2f(va.w);
    }
    ushort4 o;
    o.x = f2b(ax); o.y = f2b(ay); o.z = f2b(az); o.w = f2b(aw);
    ((ushort4*)out)[self] = o;
}

// ---------------- MFMA GEMM: Z = f(A) @ W, [M x 128]x[128 x 128], bf16 in, bf16 out --
// MODE 0: f(x)=x    MODE 1: f(x)=relu(x*a+b) per input column k
// Also emits per-block column stats (sum, sumsq of f32 accumulators) to `partial`.
template <int MODE>
__global__ __launch_bounds__(256) void mfma_gemm_kernel(
    const ushort* __restrict__ A, const ushort* __restrict__ Bt,
    const float* __restrict__ av, const float* __restrict__ bv,
    ushort* __restrict__ Z, float* __restrict__ partial, int M) {
    __shared__ float lstat[256];
    int tid = threadIdx.x;
    int lane = tid & 63;
    int wid = tid >> 6;
    int wr = wid >> 1, wc = wid & 1;
    int rowBase = blockIdx.x * 128 + wr * 64;
    int colBase = wc * 64;
    int l15 = lane & 15;
    int lk = (lane >> 4) * 8;  // k sub-offset: 0,8,16,24

    // B fragments: B[k][n], lane holds B[lk+j][colBase+n*16+l15]; Bt is [n][k]
    short8 bfr[4][4];
#pragma unroll
    for (int n = 0; n < 4; n++)
#pragma unroll
        for (int ks = 0; ks < 4; ks++)
            bfr[n][ks] = *(const short8*)(Bt + (size_t)(colBase + n * 16 + l15) * 128 + ks * 32 + lk);

    f32x4 acc[4][4];
#pragma unroll
    for (int m = 0; m < 4; m++)
#pragma unroll
        for (int n = 0; n < 4; n++) acc[m][n] = (f32x4){0.f, 0.f, 0.f, 0.f};

#pragma unroll
    for (int ks = 0; ks < 4; ks++) {
        float a8[8], b8[8];
        if (MODE == 1) {
#pragma unroll
            for (int jj = 0; jj < 8; jj++) {
                a8[jj] = av[ks * 32 + lk + jj];
                b8[jj] = bv[ks * 32 + lk + jj];
            }
        }
#pragma unroll
        for (int m = 0; m < 4; m++) {
            int row = rowBase + m * 16 + l15;
            short8 af = {0, 0, 0, 0, 0, 0, 0, 0};
            if (row < M) {
                af = *(const short8*)(A + (size_t)row * 128 + ks * 32 + lk);
                if (MODE == 1) {
#pragma unroll
                    for (int jj = 0; jj < 8; jj++) {
                        float v = b2f((unsigned short)af[jj]);
                        v = fmaxf(v * a8[jj] + b8[jj], 0.f);
                        af[jj] = (short)f2b(v);
                    }
                }
            }
#pragma unroll
            for (int n = 0; n < 4; n++)
                acc[m][n] = __builtin_amdgcn_mfma_f32_16x16x32_bf16(af, bfr[n][ks], acc[m][n], 0, 0, 0);
        }
    }

    // column stats: sum over this wave's 64 rows per column, combine in LDS
    lstat[tid] = 0.f;
    __syncthreads();
#pragma unroll
    for (int n = 0; n < 4; n++) {
        float s = 0.f, ss = 0.f;
#pragma unroll
        for (int m = 0; m < 4; m++)
#pragma unroll
            for (int r = 0; r < 4; r++) {
                float v = acc[m][n][r];
                s += v;
                ss += v * v;
            }
        s += __shfl_xor(s, 16);
        ss += __shfl_xor(ss, 16);
        s += __shfl_xor(s, 32);
        ss += __shfl_xor(ss, 32);
        if ((lane & 48) == 0) {  // lanes 0..15
            atomicAdd(&lstat[colBase + n * 16 + l15], s);
            atomicAdd(&lstat[128 + colBase + n * 16 + l15], ss);
        }
    }
    __syncthreads();
    partial[(size_t)blockIdx.x * 256 + tid] = lstat[tid];

    // store Z (bf16). D layout: row=(lane>>4)*4+r, col=lane&15 within 16x16 frag
#pragma unroll
    for (int m = 0; m < 4; m++) {
#pragma unroll
        for (int r = 0; r < 4; r++) {
            int row = rowBase + m * 16 + (lane >> 4) * 4 + r;
            if (row < M) {
#pragma unroll
                for (int n = 0; n < 4; n++)
                    Z[(size_t)row * 128 + colBase + n * 16 + l15] = f2b(acc[m][n][r]);
            }
        }
    }
}

// ---------------- BN finalize from per-block partials ----------------
__global__ void fin_kernel(const float* __restrict__ partial, int nblk,
                           const float* __restrict__ gamma, const float* __restrict__ beta,
                           float* __restrict__ a, float* __restrict__ b, float invN) {
    int c = blockIdx.x;   // column 0..127
    int t = threadIdx.x;  // 64
    float s = 0.f, ss = 0.f;
    for (int j = t; j < nblk; j += 64) {
        s += partial[(size_t)j * 256 + c];
        ss += partial[(size_t)j * 256 + 128 + c];
    }
    for (int off = 32; off >= 1; off >>= 1) {
        s += __shfl_down(s, off);
        ss += __shfl_down(ss, off);
    }
    if (t == 0) {
        float m = s * invN;
        float v = fmaxf(ss * invN - m * m, 0.f);
        float inv = rsqrtf(v + BN_EPS);
        float ac = gamma[c] * inv;
        a[c] = ac;
        b[c] = beta[c] - m * ac;
    }
}

// ---------------- elementwise: out = relu(in*a + b), bf16 ----------------
__global__ __launch_bounds__(256) void elem_bf16_kernel(const ushort* __restrict__ in,
                                                        const float* __restrict__ a,
                                                        const float* __restrict__ b,
                                                        ushort* __restrict__ out) {
    int i = blockIdx.x * 256 + threadIdx.x;  // per 8 elements
    if (i >= N_NODES * DIM / 8) return;
    uint4 u = ((const uint4*)in)[i];
    int c = (i * 8) & 127;
    unsigned int w[4] = {u.x, u.y, u.z, u.w};
    unsigned int o[4];
#pragma unroll
    for (int q = 0; q < 4; q++) {
        float lo = b2f((unsigned short)(w[q] & 0xffffu));
        float hi = b2f((unsigned short)(w[q] >> 16));
        lo = fmaxf(lo * a[c + 2 * q] + b[c + 2 * q], 0.f);
        hi = fmaxf(hi * a[c + 2 * q + 1] + b[c + 2 * q + 1], 0.f);
        o[q] = (unsigned int)f2b(lo) | ((unsigned int)f2b(hi) << 16);
    }
    uint4 ov = {o[0], o[1], o[2], o[3]};
    ((uint4*)out)[i] = ov;
}

// ---------------- pooling ----------------
__global__ void pool_f32_kernel(const float* __restrict__ h, const int* __restrict__ gptr,
                                float* __restrict__ pooled) {
    int g = blockIdx.x, d = threadIdx.x;
    int r = gptr[g], r1 = gptr[g + 1];
    float acc = 0.f;
    for (; r + 3 < r1; r += 4)
        acc += h[(size_t)r * 128 + d] + h[(size_t)(r + 1) * 128 + d] +
               h[(size_t)(r + 2) * 128 + d] + h[(size_t)(r + 3) * 128 + d];
    for (; r < r1; r++) acc += h[(size_t)r * 128 + d];
    pooled[(size_t)g * 128 + d] = acc;
}

__global__ void pool_bf16_kernel(const ushort* __restrict__ h, const int* __restrict__ gptr,
                                 float* __restrict__ pooled) {
    int g = blockIdx.x, d = threadIdx.x;
    int r = gptr[g], r1 = gptr[g + 1];
    float acc = 0.f;
    for (; r + 3 < r1; r += 4)
        acc += b2f(h[(size_t)r * 128 + d]) + b2f(h[(size_t)(r + 1) * 128 + d]) +
               b2f(h[(size_t)(r + 2) * 128 + d]) + b2f(h[(size_t)(r + 3) * 128 + d]);
    for (; r < r1; r++) acc += b2f(h[(size_t)r * 128 + d]);
    pooled[(size_t)g * 128 + d] = acc;
}

// ---------------- score + log_softmax ----------------
__global__ void score_kernel(const float* __restrict__ pooled, const float* __restrict__ Wp,
                             const float* __restrict__ bp, float* __restrict__ out) {
    int g = blockIdx.x;
    int lane = threadIdx.x;  // 64
    int o = lane & 15, q = lane >> 4;
    float acc = 0.f;
    for (int i = 0; i < N_LAYERS + 1; i++) {
        const float* pr = pooled + (size_t)i * N_GRAPH * 128 + (size_t)g * 128;
        const float* wp = Wp + (size_t)i * 128 * 16;
#pragma unroll 8
        for (int d = q * 32; d < q * 32 + 32; d++) acc += pr[d] * wp[d * 16 + o];
    }
    acc += __shfl_xor(acc, 16);
    acc += __shfl_xor(acc, 32);
    float bsum = 0.f;
#pragma unroll
    for (int i = 0; i < N_LAYERS + 1; i++) bsum += bp[i * 16 + o];
    float s = acc + bsum;
    float m = s;
    for (int off = 8; off >= 1; off >>= 1) m = fmaxf(m, __shfl_xor(m, off, 16));
    float e = expf(s - m);
    float se = e;
    for (int off = 8; off >= 1; off >>= 1) se += __shfl_xor(se, off, 16);
    if (lane < 16) {
        out[g * 16 + o] = s - m - logf(se);
        out[(size_t)N_GRAPH * 16 + g * 16 + o] = s;
    }
}

extern "C" void kernel_launch(void* const* d_in, const int* in_sizes, int n_in,
                              void* d_out, int out_size, void* d_ws, size_t ws_size,
                              hipStream_t stream) {
    (void)in_sizes; (void)n_in; (void)out_size; (void)ws_size;
    const float* feat  = (const float*)d_in[0];
    const float* W1    = (const float*)d_in[1];
    const float* W2    = (const float*)d_in[2];
    const float* g_mlp = (const float*)d_in[3];
    const float* b_mlp = (const float*)d_in[4];
    const float* g_out = (const float*)d_in[5];
    const float* b_out = (const float*)d_in[6];
    const float* Wp    = (const float*)d_in[7];
    const float* bp    = (const float*)d_in[8];
    const int*   src   = (const int*)d_in[9];
    const int*   dst   = (const int*)d_in[10];
    const int*   gid   = (const int*)d_in[11];
    float* out = (float*)d_out;

    const int N = N_NODES, E = N_EDGES, G = N_GRAPH;
    char* w = (char*)d_ws;
    size_t off = 0;
    auto alloc = [&](size_t bytes) -> char* {
        char* p = w + off;
        off = (off + bytes + 255) & ~(size_t)255;
        return p;
    };
    ushort* hb     = (ushort*)alloc((size_t)N * DIM * 2);  // h (post-activation), bf16
    ushort* agg    = (ushort*)alloc((size_t)N * DIM * 2);  // agg / h_raw, bf16
    ushort* zb     = (ushort*)alloc((size_t)N * DIM * 2);  // z (GEMM1 out), bf16
    ushort* Wt     = (ushort*)alloc((size_t)8 * 128 * 128 * 2);
    int*    csr    = (int*)alloc((size_t)E * 4);
    int*    ptr    = (int*)alloc((size_t)(N + 1) * 4);
    int*    cursor = (int*)alloc((size_t)N * 4);
    int*    deg    = (int*)alloc((size_t)N * 4);
    int*    bsum   = (int*)alloc(128 * 4);
    int*    gptr   = (int*)alloc((G + 1) * 4);
    float*  pooled = (float*)alloc((size_t)(N_LAYERS + 1) * G * DIM * 4);
    float*  partial= (float*)alloc((size_t)GEMM_BLOCKS * 256 * 4);
    float*  ab     = (float*)alloc(4 * 128 * 4);  // a1 b1 a2 b2

    const int nScanBlocks = (N + 1023) / 1024;
    const float invN = 1.f / (float)N;

    // CSR build
    hipMemsetAsync(deg, 0, (size_t)N * 4, stream);
    hist_kernel<<<(E + 255) / 256, 256, 0, stream>>>(dst, deg, E);
    scan1_kernel<<<nScanBlocks, 1024, 0, stream>>>(deg, ptr, bsum, N);
    scan2_kernel<<<1, 128, 0, stream>>>(bsum, ptr, nScanBlocks, N);
    scan3_kernel<<<(N + 255) / 256, 256, 0, stream>>>(ptr, cursor, bsum, N);
    fill_kernel<<<(E + 255) / 256, 256, 0, stream>>>(src, dst, cursor, csr, E);
    gptr_kernel<<<3, 256, 0, stream>>>(gid, gptr, N, G);

    // conversions
    cvt_feat_kernel<<<N * DIM / 4 / 256, 256, 0, stream>>>(feat, hb);
    cvtw_kernel<<<1024, 128, 0, stream>>>(W1, W2, Wt);

    // layer 0 readout pooled from exact f32 feat
    pool_f32_kernel<<<G, 128, 0, stream>>>(feat, gptr, pooled);

    for (int i = 0; i < N_LAYERS; i++) {
        spmm_bf16_kernel<<<N * 32 / 256, 256, 0, stream>>>(hb, ptr, csr, agg);
        mfma_gemm_kernel<0><<<GEMM_BLOCKS, 256, 0, stream>>>(
            agg, Wt + (size_t)i * 16384, nullptr, nullptr, zb, partial, N);
        fin_kernel<<<128, 64, 0, stream>>>(partial, GEMM_BLOCKS, g_mlp + (size_t)i * DIM,
                                           b_mlp + (size_t)i * DIM, ab, ab + 128, invN);
        mfma_gemm_kernel<1><<<GEMM_BLOCKS, 256, 0, stream>>>(
            zb, Wt + (size_t)(4 + i) * 16384, ab, ab + 128, agg, partial, N);
        fin_kernel<<<128, 64, 0, stream>>>(partial, GEMM_BLOCKS, g_out + (size_t)i * DIM,
                                           b_out + (size_t)i * DIM, ab + 256, ab + 384, invN);
        elem_bf16_kernel<<<N * DIM / 8 / 256, 256, 0, stream>>>(agg, ab + 256, ab + 384, hb);
        pool_bf16_kernel<<<G, 128, 0, stream>>>(hb, gptr, pooled + (size_t)(i + 1) * G * DIM);
    }
    score_kernel<<<G, 64, 0, stream>>>(pooled, Wp, bp, out);
}

// Round 3
// 693.549 us; speedup vs baseline: 3.0910x; 1.3626x over previous
//
#include <hip/hip_runtime.h>

#define N_NODES 100000
#define N_EDGES 1600000
#define DIM 128
#define N_GRAPH 512
#define N_LAYERS 4
#define BN_EPS 1e-5f
#define GEMM_BLOCKS ((N_NODES + 127) / 128)  // 782
#define NB 512        // CSR buckets
#define BW 196        // nodes per bucket (512*196 = 100352 >= N)
#define PA_CHUNK 4096

typedef __attribute__((ext_vector_type(8))) short short8;
typedef __attribute__((ext_vector_type(4))) float f32x4;

__device__ __forceinline__ float b2f(unsigned short u) {
    union { unsigned int i; float f; } x;
    x.i = ((unsigned int)u) << 16;
    return x.f;
}
__device__ __forceinline__ unsigned short f2b(float f) {
    union { float f; unsigned int i; } x;
    x.f = f;
    unsigned int r = x.i + 0x7FFFu + ((x.i >> 16) & 1u);  // RNE
    return (unsigned short)(r >> 16);
}

// ================= CSR build (bucketed, write-locality-friendly) =================
// Pass 1: bucket histogram (LDS) over dst>>?  (bucket = dst / BW)
__global__ __launch_bounds__(256) void hist512_kernel(const int* __restrict__ dst,
                                                      int* __restrict__ gcnt, int E) {
    __shared__ int cnt[NB];
    int t = threadIdx.x;
    for (int i = t; i < NB; i += 256) cnt[i] = 0;
    __syncthreads();
    for (int e = blockIdx.x * 256 + t; e < E; e += 256 * 256)
        atomicAdd(&cnt[dst[e] / BW], 1);
    __syncthreads();
    for (int i = t; i < NB; i += 256)
        if (cnt[i]) atomicAdd(&gcnt[i], cnt[i]);
}

// Pass 2: exclusive scan over NB buckets; init bucket cursors; ptr[N]=E
__global__ __launch_bounds__(NB) void scan512_kernel(const int* __restrict__ gcnt,
                                                     int* __restrict__ base,
                                                     int* __restrict__ gcur,
                                                     int* __restrict__ ptr) {
    __shared__ int tmp[NB];
    int t = threadIdx.x;
    int v = gcnt[t];
    tmp[t] = v;
    __syncthreads();
    int acc = v;
    for (int off = 1; off < NB; off <<= 1) {
        int add = (t >= off) ? tmp[t - off] : 0;
        __syncthreads();
        acc += add;
        tmp[t] = acc;
        __syncthreads();
    }
    int ex = acc - v;
    base[t] = ex;
    gcur[t] = ex;
    if (t == NB - 1) ptr[N_NODES] = ex + v;
}

// Pass 3: scatter (src,dst) pairs into bucket regions
__global__ __launch_bounds__(256) void phaseA_kernel(const int* __restrict__ src,
                                                     const int* __restrict__ dst,
                                                     int* __restrict__ gcur,
                                                     int2* __restrict__ bb, int E) {
    __shared__ int cnt[NB];
    __shared__ int cur[NB];
    int t = threadIdx.x;
    int e0 = blockIdx.x * PA_CHUNK;
    for (int i = t; i < NB; i += 256) cnt[i] = 0;
    __syncthreads();
#pragma unroll
    for (int i = 0; i < PA_CHUNK / 256; i++) {
        int e = e0 + t + i * 256;
        if (e < E) atomicAdd(&cnt[dst[e] / BW], 1);
    }
    __syncthreads();
    for (int i = t; i < NB; i += 256) {
        int c = cnt[i];
        cur[i] = c ? atomicAdd(&gcur[i], c) : 0;
    }
    __syncthreads();
#pragma unroll
    for (int i = 0; i < PA_CHUNK / 256; i++) {
        int e = e0 + t + i * 256;
        if (e < E) {
            int d = dst[e];
            int b = d / BW;
            int pos = atomicAdd(&cur[b], 1);
            bb[pos] = make_int2(src[e], d);
        }
    }
}

// Pass 4: per-bucket fine scatter — one block per bucket. Local hist + scan gives
// per-node ptr; csr writes stay within one ~13 KB region owned by this block.
__global__ __launch_bounds__(256) void phaseB_kernel(const int2* __restrict__ bb,
                                                     const int* __restrict__ base,
                                                     const int* __restrict__ gcnt,
                                                     int* __restrict__ ptr,
                                                     int* __restrict__ csr) {
    __shared__ int cnt[256];
    __shared__ int cur[256];
    __shared__ int tmp[256];
    int b = blockIdx.x, t = threadIdx.x;
    int n0 = b * BW;
    int e0 = base[b], ec = gcnt[b];
    cnt[t] = 0;
    __syncthreads();
    for (int j = t; j < ec; j += 256) atomicAdd(&cnt[bb[e0 + j].y - n0], 1);
    __syncthreads();
    int v = cnt[t];
    tmp[t] = v;
    __syncthreads();
    int acc = v;
    for (int off = 1; off < 256; off <<= 1) {
        int add = (t >= off) ? tmp[t - off] : 0;
        __syncthreads();
        acc += add;
        tmp[t] = acc;
        __syncthreads();
    }
    int ex = acc - v;
    int node = n0 + t;
    if (t < BW && node < N_NODES) ptr[node] = e0 + ex;
    cur[t] = e0 + ex;
    __syncthreads();
    for (int j = t; j < ec; j += 256) {
        int2 p = bb[e0 + j];
        int slot = atomicAdd(&cur[p.y - n0], 1);
        csr[slot] = p.x;
    }
}

__global__ void gptr_kernel(const int* __restrict__ gid, int* __restrict__ gptr, int N, int G) {
    int g = blockIdx.x * 256 + threadIdx.x;
    if (g > G) return;
    int lo = 0, hi = N;
    while (lo < hi) {
        int mid = (lo + hi) >> 1;
        if (gid[mid] < g) lo = mid + 1; else hi = mid;
    }
    gptr[g] = lo;
}

// ================= conversions =================
__global__ void cvt_feat_kernel(const float* __restrict__ f, ushort* __restrict__ o) {
    int i = blockIdx.x * 256 + threadIdx.x;  // per 4 elements
    if (i >= N_NODES * DIM / 4) return;
    float4 v = ((const float4*)f)[i];
    ushort4 u;
    u.x = f2b(v.x); u.y = f2b(v.y); u.z = f2b(v.z); u.w = f2b(v.w);
    ((ushort4*)o)[i] = u;
}

// Wt[mat][n][k] = W[mat][k][n]  (bf16, transposed for MFMA B-operand)
__global__ void cvtw_kernel(const float* __restrict__ W1, const float* __restrict__ W2,
                            ushort* __restrict__ Wt) {
    int blk = blockIdx.x;  // mat*128 + k
    int mat = blk >> 7, k = blk & 127;
    int n = threadIdx.x;
    const float* W = (mat < 4) ? (W1 + (size_t)mat * 16384) : (W2 + (size_t)(mat - 4) * 16384);
    Wt[(size_t)mat * 16384 + n * 128 + k] = f2b(W[k * 128 + n]);
}

// ================= SpMM with fused activation =================
// out[n] = f(X[n]) + sum_{j in in(n)} f(X[csr[j]]),  f = MODE ? relu(x*a+b) : x
template <int MODE>
__device__ __forceinline__ void accum8(float* acc, uint4 v, const float* a8, const float* b8) {
    unsigned w[4] = {v.x, v.y, v.z, v.w};
#pragma unroll
    for (int q = 0; q < 4; q++) {
        float lo = __uint_as_float(w[q] << 16);
        float hi = __uint_as_float(w[q] & 0xffff0000u);
        if (MODE) {
            lo = fmaxf(fmaf(lo, a8[2 * q], b8[2 * q]), 0.f);
            hi = fmaxf(fmaf(hi, a8[2 * q + 1], b8[2 * q + 1]), 0.f);
        }
        acc[2 * q] += lo;
        acc[2 * q + 1] += hi;
    }
}

template <int MODE>
__global__ __launch_bounds__(256) void spmm_kernel(const ushort* __restrict__ X,
                                                   const int* __restrict__ ptr,
                                                   const int* __restrict__ csr,
                                                   const float* __restrict__ av,
                                                   const float* __restrict__ bv,
                                                   ushort* __restrict__ out) {
    int t = blockIdx.x * 256 + threadIdx.x;
    int node = t >> 4;  // 16 lanes per node, 16 B per lane
    int l = t & 15;
    if (node >= N_NODES) return;
    const uint4* hp = (const uint4*)X;
    float a8[8], b8[8];
    if (MODE) {
#pragma unroll
        for (int j = 0; j < 8; j++) {
            a8[j] = av[l * 8 + j];
            b8[j] = bv[l * 8 + j];
        }
    }
    float acc[8] = {0.f, 0.f, 0.f, 0.f, 0.f, 0.f, 0.f, 0.f};
    size_t self = (size_t)node * 16 + l;
    accum8<MODE>(acc, hp[self], a8, b8);
    int j = ptr[node], s1 = ptr[node + 1];
    for (; j + 3 < s1; j += 4) {
        int i0 = csr[j], i1 = csr[j + 1], i2 = csr[j + 2], i3 = csr[j + 3];
        uint4 v0 = hp[(size_t)i0 * 16 + l];
        uint4 v1 = hp[(size_t)i1 * 16 + l];
        uint4 v2 = hp[(size_t)i2 * 16 + l];
        uint4 v3 = hp[(size_t)i3 * 16 + l];
        accum8<MODE>(acc, v0, a8, b8);
        accum8<MODE>(acc, v1, a8, b8);
        accum8<MODE>(acc, v2, a8, b8);
        accum8<MODE>(acc, v3, a8, b8);
    }
    for (; j < s1; j++) accum8<MODE>(acc, hp[(size_t)csr[j] * 16 + l], a8, b8);
    uint4 o;
    unsigned* op = (unsigned*)&o;
#pragma unroll
    for (int q = 0; q < 4; q++)
        op[q] = (unsigned)f2b(acc[2 * q]) | ((unsigned)f2b(acc[2 * q + 1]) << 16);
    ((uint4*)out)[self] = o;
}

// ================= MFMA GEMM (bf16): Z = f(A) @ W + column stats =================
template <int MODE>
__global__ __launch_bounds__(256) void mfma_gemm_kernel(
    const ushort* __restrict__ A, const ushort* __restrict__ Bt,
    const float* __restrict__ av, const float* __restrict__ bv,
    ushort* __restrict__ Z, float* __restrict__ partial, int M) {
    __shared__ float lstat[256];
    int tid = threadIdx.x;
    int lane = tid & 63;
    int wid = tid >> 6;
    int wr = wid >> 1, wc = wid & 1;
    int rowBase = blockIdx.x * 128 + wr * 64;
    int colBase = wc * 64;
    int l15 = lane & 15;
    int lk = (lane >> 4) * 8;

    short8 bfr[4][4];
#pragma unroll
    for (int n = 0; n < 4; n++)
#pragma unroll
        for (int ks = 0; ks < 4; ks++)
            bfr[n][ks] = *(const short8*)(Bt + (size_t)(colBase + n * 16 + l15) * 128 + ks * 32 + lk);

    f32x4 acc[4][4];
#pragma unroll
    for (int m = 0; m < 4; m++)
#pragma unroll
        for (int n = 0; n < 4; n++) acc[m][n] = (f32x4){0.f, 0.f, 0.f, 0.f};

#pragma unroll
    for (int ks = 0; ks < 4; ks++) {
        float a8[8], b8[8];
        if (MODE == 1) {
#pragma unroll
            for (int jj = 0; jj < 8; jj++) {
                a8[jj] = av[ks * 32 + lk + jj];
                b8[jj] = bv[ks * 32 + lk + jj];
            }
        }
#pragma unroll
        for (int m = 0; m < 4; m++) {
            int row = rowBase + m * 16 + l15;
            short8 af = {0, 0, 0, 0, 0, 0, 0, 0};
            if (row < M) {
                af = *(const short8*)(A + (size_t)row * 128 + ks * 32 + lk);
                if (MODE == 1) {
#pragma unroll
                    for (int jj = 0; jj < 8; jj++) {
                        float v = b2f((unsigned short)af[jj]);
                        v = fmaxf(fmaf(v, a8[jj], b8[jj]), 0.f);
                        af[jj] = (short)f2b(v);
                    }
                }
            }
#pragma unroll
            for (int n = 0; n < 4; n++)
                acc[m][n] = __builtin_amdgcn_mfma_f32_16x16x32_bf16(af, bfr[n][ks], acc[m][n], 0, 0, 0);
        }
    }

    lstat[tid] = 0.f;
    __syncthreads();
#pragma unroll
    for (int n = 0; n < 4; n++) {
        float s = 0.f, ss = 0.f;
#pragma unroll
        for (int m = 0; m < 4; m++)
#pragma unroll
            for (int r = 0; r < 4; r++) {
                float v = acc[m][n][r];
                s += v;
                ss += v * v;
            }
        s += __shfl_xor(s, 16);
        ss += __shfl_xor(ss, 16);
        s += __shfl_xor(s, 32);
        ss += __shfl_xor(ss, 32);
        if ((lane & 48) == 0) {
            atomicAdd(&lstat[colBase + n * 16 + l15], s);
            atomicAdd(&lstat[128 + colBase + n * 16 + l15], ss);
        }
    }
    __syncthreads();
    partial[(size_t)blockIdx.x * 256 + tid] = lstat[tid];

#pragma unroll
    for (int m = 0; m < 4; m++) {
#pragma unroll
        for (int r = 0; r < 4; r++) {
            int row = rowBase + m * 16 + (lane >> 4) * 4 + r;
            if (row < M) {
#pragma unroll
                for (int n = 0; n < 4; n++)
                    Z[(size_t)row * 128 + colBase + n * 16 + l15] = f2b(acc[m][n][r]);
            }
        }
    }
}

// ================= BN finalize =================
__global__ void fin_kernel(const float* __restrict__ partial, int nblk,
                           const float* __restrict__ gamma, const float* __restrict__ beta,
                           float* __restrict__ a, float* __restrict__ b, float invN) {
    int c = blockIdx.x;
    int t = threadIdx.x;
    float s = 0.f, ss = 0.f;
    for (int j = t; j < nblk; j += 64) {
        s += partial[(size_t)j * 256 + c];
        ss += partial[(size_t)j * 256 + 128 + c];
    }
    for (int off = 32; off >= 1; off >>= 1) {
        s += __shfl_down(s, off);
        ss += __shfl_down(ss, off);
    }
    if (t == 0) {
        float m = s * invN;
        float v = fmaxf(ss * invN - m * m, 0.f);
        float inv = rsqrtf(v + BN_EPS);
        float ac = gamma[c] * inv;
        a[c] = ac;
        b[c] = beta[c] - m * ac;
    }
}

// ================= pooling =================
__global__ void pool_f32_kernel(const float* __restrict__ h, const int* __restrict__ gptr,
                                float* __restrict__ pooled) {
    int g = blockIdx.x, d = threadIdx.x;
    int r = gptr[g], r1 = gptr[g + 1];
    float acc = 0.f;
    for (; r + 3 < r1; r += 4)
        acc += h[(size_t)r * 128 + d] + h[(size_t)(r + 1) * 128 + d] +
               h[(size_t)(r + 2) * 128 + d] + h[(size_t)(r + 3) * 128 + d];
    for (; r < r1; r++) acc += h[(size_t)r * 128 + d];
    pooled[(size_t)g * 128 + d] = acc;
}

// pool with fused activation: pooled[g][d] = sum relu(x*a+b)
__global__ void pool_act_kernel(const ushort* __restrict__ X, const int* __restrict__ gptr,
                                const float* __restrict__ av, const float* __restrict__ bv,
                                float* __restrict__ pooled) {
    int g = blockIdx.x, d = threadIdx.x;
    float a = av[d], b = bv[d];
    int r = gptr[g], r1 = gptr[g + 1];
    float acc = 0.f;
    for (; r + 3 < r1; r += 4) {
        float x0 = b2f(X[(size_t)r * 128 + d]);
        float x1 = b2f(X[(size_t)(r + 1) * 128 + d]);
        float x2 = b2f(X[(size_t)(r + 2) * 128 + d]);
        float x3 = b2f(X[(size_t)(r + 3) * 128 + d]);
        acc += fmaxf(fmaf(x0, a, b), 0.f) + fmaxf(fmaf(x1, a, b), 0.f) +
               fmaxf(fmaf(x2, a, b), 0.f) + fmaxf(fmaf(x3, a, b), 0.f);
    }
    for (; r < r1; r++) acc += fmaxf(fmaf(b2f(X[(size_t)r * 128 + d]), a, b), 0.f);
    pooled[(size_t)g * 128 + d] = acc;
}

// ================= score + log_softmax =================
__global__ void score_kernel(const float* __restrict__ pooled, const float* __restrict__ Wp,
                             const float* __restrict__ bp, float* __restrict__ out) {
    int g = blockIdx.x;
    int lane = threadIdx.x;
    int o = lane & 15, q = lane >> 4;
    float acc = 0.f;
    for (int i = 0; i < N_LAYERS + 1; i++) {
        const float* pr = pooled + (size_t)i * N_GRAPH * 128 + (size_t)g * 128;
        const float* wp = Wp + (size_t)i * 128 * 16;
#pragma unroll 8
        for (int d = q * 32; d < q * 32 + 32; d++) acc += pr[d] * wp[d * 16 + o];
    }
    acc += __shfl_xor(acc, 16);
    acc += __shfl_xor(acc, 32);
    float bsum = 0.f;
#pragma unroll
    for (int i = 0; i < N_LAYERS + 1; i++) bsum += bp[i * 16 + o];
    float s = acc + bsum;
    float m = s;
    for (int off = 8; off >= 1; off >>= 1) m = fmaxf(m, __shfl_xor(m, off, 16));
    float e = expf(s - m);
    float se = e;
    for (int off = 8; off >= 1; off >>= 1) se += __shfl_xor(se, off, 16);
    if (lane < 16) {
        out[g * 16 + o] = s - m - logf(se);
        out[(size_t)N_GRAPH * 16 + g * 16 + o] = s;
    }
}

extern "C" void kernel_launch(void* const* d_in, const int* in_sizes, int n_in,
                              void* d_out, int out_size, void* d_ws, size_t ws_size,
                              hipStream_t stream) {
    (void)in_sizes; (void)n_in; (void)out_size; (void)ws_size;
    const float* feat  = (const float*)d_in[0];
    const float* W1    = (const float*)d_in[1];
    const float* W2    = (const float*)d_in[2];
    const float* g_mlp = (const float*)d_in[3];
    const float* b_mlp = (const float*)d_in[4];
    const float* g_out = (const float*)d_in[5];
    const float* b_out = (const float*)d_in[6];
    const float* Wp    = (const float*)d_in[7];
    const float* bp    = (const float*)d_in[8];
    const int*   src   = (const int*)d_in[9];
    const int*   dst   = (const int*)d_in[10];
    const int*   gid   = (const int*)d_in[11];
    float* out = (float*)d_out;

    const int N = N_NODES, E = N_EDGES, G = N_GRAPH;
    char* w = (char*)d_ws;
    size_t off = 0;
    auto alloc = [&](size_t bytes) -> char* {
        char* p = w + off;
        off = (off + bytes + 255) & ~(size_t)255;
        return p;
    };
    ushort* X      = (ushort*)alloc((size_t)N * DIM * 2);  // raw node features (bf16)
    ushort* T      = (ushort*)alloc((size_t)N * DIM * 2);  // spmm output
    ushort* Z      = (ushort*)alloc((size_t)N * DIM * 2);  // gemm1 output (aliased: bucketBuf)
    ushort* Wt     = (ushort*)alloc((size_t)8 * 128 * 128 * 2);
    int*    csr    = (int*)alloc((size_t)E * 4);
    int*    ptr    = (int*)alloc((size_t)(N + 1) * 4);
    int*    gcnt   = (int*)alloc(NB * 4);
    int*    bbase  = (int*)alloc(NB * 4);
    int*    gcur   = (int*)alloc(NB * 4);
    int*    gptr   = (int*)alloc((G + 1) * 4);
    float*  pooled = (float*)alloc((size_t)(N_LAYERS + 1) * G * DIM * 4);
    float*  partial= (float*)alloc((size_t)GEMM_BLOCKS * 256 * 4);
    float*  ab     = (float*)alloc(4 * 128 * 4);  // aZ bZ aX bX
    int2*   bb     = (int2*)Z;  // bucket buffer aliases Z (only used before first gemm)

    const float invN = 1.f / (float)N;
    float* abZ = ab;
    float* abX = ab + 256;

    // ---- CSR build ----
    hipMemsetAsync(gcnt, 0, NB * 4, stream);
    hist512_kernel<<<256, 256, 0, stream>>>(dst, gcnt, E);
    scan512_kernel<<<1, NB, 0, stream>>>(gcnt, bbase, gcur, ptr);
    phaseA_kernel<<<(E + PA_CHUNK - 1) / PA_CHUNK, 256, 0, stream>>>(src, dst, gcur, bb, E);
    phaseB_kernel<<<NB, 256, 0, stream>>>(bb, bbase, gcnt, ptr, csr);
    gptr_kernel<<<3, 256, 0, stream>>>(gid, gptr, N, G);

    // ---- conversions + layer-0 readout ----
    cvt_feat_kernel<<<N * DIM / 4 / 256, 256, 0, stream>>>(feat, X);
    cvtw_kernel<<<1024, 128, 0, stream>>>(W1, W2, Wt);
    pool_f32_kernel<<<G, 128, 0, stream>>>(feat, gptr, pooled);

    // ---- layers ----
    const int spmmGrid = N * 16 / 256;  // 6250
    for (int i = 0; i < N_LAYERS; i++) {
        if (i == 0)
            spmm_kernel<0><<<spmmGrid, 256, 0, stream>>>(X, ptr, csr, nullptr, nullptr, T);
        else
            spmm_kernel<1><<<spmmGrid, 256, 0, stream>>>(X, ptr, csr, abX, abX + 128, T);
        mfma_gemm_kernel<0><<<GEMM_BLOCKS, 256, 0, stream>>>(
            T, Wt + (size_t)i * 16384, nullptr, nullptr, Z, partial, N);
        fin_kernel<<<128, 64, 0, stream>>>(partial, GEMM_BLOCKS, g_mlp + (size_t)i * DIM,
                                           b_mlp + (size_t)i * DIM, abZ, abZ + 128, invN);
        mfma_gemm_kernel<1><<<GEMM_BLOCKS, 256, 0, stream>>>(
            Z, Wt + (size_t)(4 + i) * 16384, abZ, abZ + 128, X, partial, N);
        fin_kernel<<<128, 64, 0, stream>>>(partial, GEMM_BLOCKS, g_out + (size_t)i * DIM,
                                           b_out + (size_t)i * DIM, abX, abX + 128, invN);
        pool_act_kernel<<<G, 128, 0, stream>>>(X, gptr, abX, abX + 128,
                                               pooled + (size_t)(i + 1) * G * DIM);
    }
    score_kernel<<<G, 64, 0, stream>>>(pooled, Wp, bp, out);
}